// Round 1
// baseline (3153.112 us; speedup 1.0000x reference)
//
#include <hip/hip_runtime.h>
#include <hip/hip_bf16.h>

#define DEVI __device__ __forceinline__

#define ASR_DIM 1024
#define VOCAB   32000
#define LLM_DIM 4096
#define MROWS   8192   // 4*2048

typedef __bf16 bf16x8 __attribute__((ext_vector_type(8)));
typedef float floatx4 __attribute__((ext_vector_type(4)));
typedef unsigned short ushortx8 __attribute__((ext_vector_type(8)));

DEVI unsigned short f2bf(float f) {
    union { __hip_bfloat16 h; unsigned short u; } cv;
    cv.h = __float2bfloat16(f);
    return cv.u;
}
DEVI float bf2f(unsigned short u) {
    return __builtin_bit_cast(float, (unsigned int)u << 16);
}

// async global->LDS, 16B per lane. LDS dest: wave-uniform base + lane*16.
DEVI void async16(const unsigned short* g, unsigned short* l) {
    __builtin_amdgcn_global_load_lds(
        (const __attribute__((address_space(1))) unsigned int*)g,
        (__attribute__((address_space(3))) unsigned int*)l,
        16, 0, 0);
}

// ---------------- fp32 -> bf16 convert (8 elems/thread) ----------------
__global__ __launch_bounds__(256) void convert_kernel(
    const float* __restrict__ src, unsigned short* __restrict__ dst, int n8) {
    int i = blockIdx.x * blockDim.x + threadIdx.x;
    if (i >= n8) return;
    const float4* s4 = (const float4*)src;
    float4 a = s4[2 * i], b = s4[2 * i + 1];
    ushortx8 o;
    o[0] = f2bf(a.x); o[1] = f2bf(a.y); o[2] = f2bf(a.z); o[3] = f2bf(a.w);
    o[4] = f2bf(b.x); o[5] = f2bf(b.y); o[6] = f2bf(b.z); o[7] = f2bf(b.w);
    ((ushortx8*)dst)[i] = o;
}

// ---------------- fp32 [R][C] -> bf16 [C][R] transpose ----------------
__global__ __launch_bounds__(256) void transpose_convert_kernel(
    const float* __restrict__ src, unsigned short* __restrict__ dst, int R, int C) {
    __shared__ float tile[64][65];
    const int tid = threadIdx.x;
    const int rb = blockIdx.y * 64, cb = blockIdx.x * 64;
#pragma unroll
    for (int i = 0; i < 4; ++i) {
        int lin = tid + i * 256;
        int r = lin >> 4, c4 = (lin & 15) << 2;
        float4 v = *(const float4*)(src + (size_t)(rb + r) * C + cb + c4);
        tile[r][c4] = v.x; tile[r][c4 + 1] = v.y; tile[r][c4 + 2] = v.z; tile[r][c4 + 3] = v.w;
    }
    __syncthreads();
#pragma unroll
    for (int i = 0; i < 8; ++i) {
        int lin = tid + i * 256;
        int oc = lin >> 5, r2 = (lin & 31) << 1;
        ushort2 o;
        o.x = f2bf(tile[r2][oc]);
        o.y = f2bf(tile[r2 + 1][oc]);
        *(ushort2*)(dst + (size_t)(cb + oc) * R + rb + r2) = o;
    }
}

// ---------------- 256x256 8-phase bf16 GEMM, B^T input ----------------
// C[M,N] = A[M,K]*B[N,K]^T. BK=64, 512 thr (8 waves, 2Mx4N), per-wave 128x64.
// LDS 128KB: [buf2][A/B][half2][128x64 bf16], XOR-swizzled (colbyte ^= (row&7)<<4)
// via pre-swizzled global source (linear gload_lds dest) + swizzled ds_read.
// Schedule: 4 phases/K-tile, 16 MFMA each; 1 half-tile staged per phase;
// counted vmcnt(4) once per K-tile (phase 4), never 0 in steady state.
// EPI: 1 = bf16 out + fp32 bias add; 2 = fp32 out * rowscale[row].
template <int EPI>
__global__ __launch_bounds__(512, 2) void gemm256_kernel(
    const unsigned short* __restrict__ A, const unsigned short* __restrict__ B,
    const float* __restrict__ aux, void* __restrict__ Cout, int M, int N, int K) {
    __shared__ alignas(128) unsigned short lds[2][2][2][8192];
    const int tid  = threadIdx.x;
    const int lane = tid & 63;
    const int w    = tid >> 6;
    const int wm   = w >> 2;     // 0..1
    const int wn   = w & 3;      // 0..3

    // XCD-aware bijective swizzle (grid counts here are multiples of 8)
    const int nwg = gridDim.x * gridDim.y;
    const int bid = blockIdx.y * gridDim.x + blockIdx.x;
    const int swz = (bid & 7) * (nwg >> 3) + (bid >> 3);
    const size_t tileM = (size_t)(swz / gridDim.x) * 256;
    const size_t tileN = (size_t)(swz % gridDim.x) * 256;

    const int NT = K >> 6;       // K-tiles (even for both our GEMMs, NT>=2)
    const int l3 = lane >> 3, l7 = lane & 7;
    // staging: lane covers row (j*64 + w*8 + l3), logical col 8*((l7^l3)) .. +8
    const size_t laneofs = (size_t)l3 * K + (size_t)((l7 ^ l3) << 3);
    const unsigned short* gA = A + (tileM + (size_t)w * 8) * K + laneofs;
    const unsigned short* gB = B + (tileN + (size_t)w * 8) * K + laneofs;

#define STAGE(q, o, h, G, kt) do {                                             \
        const unsigned short* _s = (G) + (size_t)(kt) * 64 + (size_t)(h) * 128 * K; \
        async16(_s, &lds[q][o][h][w * 512]);                                   \
        async16(_s + (size_t)64 * K, &lds[q][o][h][4096 + w * 512]);           \
    } while (0)

#define BARX() do { __builtin_amdgcn_s_barrier(); __builtin_amdgcn_sched_barrier(0); } while (0)

    // prologue: tile0 fully + {HB0,HA0} of tile1 in flight
    STAGE(0, 0, 0, gA, 0);
    STAGE(0, 0, 1, gA, 0);
    STAGE(0, 1, 0, gB, 0);
    STAGE(0, 1, 1, gB, 0);
    STAGE(1, 1, 0, gB, 1);
    STAGE(1, 0, 0, gA, 1);
    asm volatile("s_waitcnt vmcnt(4)" ::: "memory");   // tile0 landed
    __builtin_amdgcn_sched_barrier(0);
    BARX();

    floatx4 acc[8][4] = {};
    bf16x8 af[4][2], b01[2][2], b23[2][2];

    const int la   = lane & 15;
    const int c0   = ((lane >> 4) << 3) ^ (l7 << 3);   // swizzled col, ks=0
    const int aro0 = la * 64 + c0;
    const int aro1 = la * 64 + (c0 ^ 32);              // ks=1
    const int bro0 = (wn & 1) * 4096 + aro0;
    const int bro1 = (wn & 1) * 4096 + aro1;

#define LDA(q, mi, ks) (*(const bf16x8*)&lds[q][0][wm][((ks) ? aro1 : aro0) + (mi) * 1024])
#define LDB(q, ni, ks) (*(const bf16x8*)&lds[q][1][wn >> 1][((ks) ? bro1 : bro0) + (ni) * 1024])

#define MM8(MI0, NI0, BFA) do {                                                \
        _Pragma("unroll") for (int _m = 0; _m < 4; ++_m)                       \
        _Pragma("unroll") for (int _n = 0; _n < 2; ++_n)                       \
        _Pragma("unroll") for (int _k = 0; _k < 2; ++_k)                       \
            acc[(MI0) + _m][(NI0) + _n] = __builtin_amdgcn_mfma_f32_16x16x32_bf16( \
                af[_m][_k], BFA[_n][_k], acc[(MI0) + _m][(NI0) + _n], 0, 0, 0); \
    } while (0)

    // phase roles (q = t&1): reads 12/4/8/0; stages: p1 HA1(t+1), p2 HB1(t+1),
    // p3 HB0(t+2), p4 HA0(t+2) -- each target region dead by that phase.
#define KTILE(q, t) do {                                                       \
        /* phase 1: quadrant (mi0-3, ni0-1) */                                 \
        _Pragma("unroll") for (int _m = 0; _m < 4; ++_m) {                     \
            af[_m][0] = LDA(q, _m, 0); af[_m][1] = LDA(q, _m, 1); }            \
        _Pragma("unroll") for (int _n = 0; _n < 2; ++_n) {                     \
            b01[_n][0] = LDB(q, _n, 0); b01[_n][1] = LDB(q, _n, 1); }          \
        if ((t) + 1 < NT) STAGE((q) ^ 1, 0, 1, gA, (t) + 1);                   \
        BARX();                                                                \
        __builtin_amdgcn_s_setprio(1); MM8(0, 0, b01); __builtin_amdgcn_s_setprio(0); \
        BARX();                                                                \
        /* phase 2: quadrant (mi0-3, ni2-3) */                                 \
        _Pragma("unroll") for (int _n = 0; _n < 2; ++_n) {                     \
            b23[_n][0] = LDB(q, 2 + _n, 0); b23[_n][1] = LDB(q, 2 + _n, 1); }  \
        if ((t) + 1 < NT) STAGE((q) ^ 1, 1, 1, gB, (t) + 1);                   \
        BARX();                                                                \
        __builtin_amdgcn_s_setprio(1); MM8(0, 2, b23); __builtin_amdgcn_s_setprio(0); \
        BARX();                                                                \
        /* phase 3: quadrant (mi4-7, ni2-3) */                                 \
        _Pragma("unroll") for (int _m = 0; _m < 4; ++_m) {                     \
            af[_m][0] = LDA(q, 4 + _m, 0); af[_m][1] = LDA(q, 4 + _m, 1); }    \
        if ((t) + 2 < NT) STAGE(q, 1, 0, gB, (t) + 2);                         \
        BARX();                                                                \
        __builtin_amdgcn_s_setprio(1); MM8(4, 2, b23); __builtin_amdgcn_s_setprio(0); \
        BARX();                                                                \
        /* phase 4: quadrant (mi4-7, ni0-1), no ds_reads */                    \
        if ((t) + 2 < NT) STAGE(q, 0, 0, gA, (t) + 2);                         \
        BARX();                                                                \
        __builtin_amdgcn_s_setprio(1); MM8(4, 0, b01); __builtin_amdgcn_s_setprio(0); \
        if ((t) + 2 < NT)      { asm volatile("s_waitcnt vmcnt(4)" ::: "memory"); } \
        else if ((t) + 1 < NT) { asm volatile("s_waitcnt vmcnt(0)" ::: "memory"); } \
        __builtin_amdgcn_sched_barrier(0);                                     \
        BARX();                                                                \
    } while (0)

    for (int t = 0; t < NT; t += 2) { KTILE(0, t); KTILE(1, t + 1); }

#undef KTILE
#undef MM8
#undef LDA
#undef LDB
#undef STAGE
#undef BARX

    // epilogue: C/D layout col=lane&15, row=(lane>>4)*4+reg
    const size_t er0 = tileM + wm * 128 + ((lane >> 4) << 2);
    const size_t ec0 = tileN + wn * 64 + la;
    if (EPI == 1) {
        unsigned short* C = (unsigned short*)Cout;
        float bv[4];
#pragma unroll
        for (int ni = 0; ni < 4; ++ni) bv[ni] = aux[ec0 + ni * 16];
#pragma unroll
        for (int mi = 0; mi < 8; ++mi)
#pragma unroll
            for (int r = 0; r < 4; ++r) {
                size_t base = (er0 + mi * 16 + r) * (size_t)N + ec0;
#pragma unroll
                for (int ni = 0; ni < 4; ++ni)
                    C[base + ni * 16] = f2bf(acc[mi][ni][r] + bv[ni]);
            }
    } else {
        float* C = (float*)Cout;
#pragma unroll
        for (int mi = 0; mi < 8; ++mi)
#pragma unroll
            for (int r = 0; r < 4; ++r) {
                const float sc = aux[er0 + mi * 16 + r];   // rowinv
                size_t base = (er0 + mi * 16 + r) * (size_t)N + ec0;
#pragma unroll
                for (int ni = 0; ni < 4; ++ni)
                    C[base + ni * 16] = acc[mi][ni][r] * sc;
            }
    }
}

// ---------------- row softmax, deferred normalization ----------------
// pass1: max; pass2: write exp(x-mx) bf16 in place + accumulate sum;
// stores 1/sum per row; GEMM2 epilogue applies it.
__global__ __launch_bounds__(256) void softmax_kernel(
    unsigned short* __restrict__ logits, float* __restrict__ rowinv, int N) {
    const int row = blockIdx.x;
    unsigned short* p = logits + (size_t)row * N;
    const int tid = threadIdx.x;
    const int n8 = N >> 3;
    __shared__ float red[8];

    float mx = -3.0e38f;
    for (int i = tid; i < n8; i += 256) {
        ushortx8 v = ((const ushortx8*)p)[i];
#pragma unroll
        for (int j = 0; j < 8; ++j) mx = fmaxf(mx, bf2f(v[j]));
    }
#pragma unroll
    for (int off = 32; off > 0; off >>= 1) mx = fmaxf(mx, __shfl_xor(mx, off));
    if ((tid & 63) == 0) red[tid >> 6] = mx;
    __syncthreads();
    mx = fmaxf(fmaxf(red[0], red[1]), fmaxf(red[2], red[3]));

    float s = 0.f;
    for (int i = tid; i < n8; i += 256) {
        ushortx8 v = ((const ushortx8*)p)[i];
        ushortx8 o;
#pragma unroll
        for (int j = 0; j < 8; ++j) {
            float e = __expf(bf2f(v[j]) - mx);
            s += e;
            o[j] = f2bf(e);
        }
        ((ushortx8*)p)[i] = o;
    }
#pragma unroll
    for (int off = 32; off > 0; off >>= 1) s += __shfl_xor(s, off);
    if ((tid & 63) == 0) red[4 + (tid >> 6)] = s;
    __syncthreads();
    if (tid == 0) rowinv[row] = 1.0f / (red[4] + red[5] + red[6] + red[7]);
}

extern "C" void kernel_launch(void* const* d_in, const int* in_sizes, int n_in,
                              void* d_out, int out_size, void* d_ws, size_t ws_size,
                              hipStream_t stream) {
    const float* asr   = (const float*)d_in[0];   // [4,2048,1024]
    const float* projw = (const float*)d_in[1];   // [32000,1024]
    const float* projb = (const float*)d_in[2];   // [32000]
    const float* embw  = (const float*)d_in[3];   // [32000,4096]

    // workspace (bf16 elems): asr | proj_w | embed_w^T | logits
    unsigned short* ws      = (unsigned short*)d_ws;
    unsigned short* asr_bf  = ws;
    unsigned short* proj_bf = asr_bf + (size_t)MROWS * ASR_DIM;
    unsigned short* et_bf   = proj_bf + (size_t)VOCAB * ASR_DIM;
    unsigned short* logits  = et_bf + (size_t)LLM_DIM * VOCAB;
    // rowinv (32KB fp32) aliases asr_bf: asr_bf's last reader is GEMM1,
    // rowinv is written by softmax (after GEMM1) and read by GEMM2. Stream-ordered.
    float* rowinv = (float*)asr_bf;

    // 1) converts
    convert_kernel<<<(MROWS * ASR_DIM / 8) / 256, 256, 0, stream>>>(
        asr, asr_bf, MROWS * ASR_DIM / 8);
    convert_kernel<<<(VOCAB * ASR_DIM / 8) / 256, 256, 0, stream>>>(
        projw, proj_bf, VOCAB * ASR_DIM / 8);
    transpose_convert_kernel<<<dim3(LLM_DIM / 64, VOCAB / 64), 256, 0, stream>>>(
        embw, et_bf, VOCAB, LLM_DIM);

    // 2) GEMM1: logits[M,V] = asr * proj_w^T + bias (bf16 out)
    gemm256_kernel<1><<<dim3(VOCAB / 256, MROWS / 256), 512, 0, stream>>>(
        asr_bf, proj_bf, projb, (void*)logits, MROWS, VOCAB, ASR_DIM);

    // 3) softmax rows (writes unnormalized exp + 1/sum per row)
    softmax_kernel<<<MROWS, 256, 0, stream>>>(logits, rowinv, VOCAB);

    // 4) GEMM2: out[M,E] = exp * (E^T)^T, scaled by rowinv in epilogue (fp32 out)
    gemm256_kernel<2><<<dim3(LLM_DIM / 256, MROWS / 256), 512, 0, stream>>>(
        logits, et_bf, rowinv, d_out, MROWS, LLM_DIM, VOCAB);
}